// Round 4
// baseline (9516.222 us; speedup 1.0000x reference)
//
#include <hip/hip_runtime.h>
#include <hip/hip_bf16.h>
#include <hip/hip_cooperative_groups.h>

namespace cg = cooperative_groups;

#define TT 128
#define BB 128
#define HH 1024
#define PP 32
#define G7 7168

typedef __attribute__((ext_vector_type(8))) short short8;
typedef __attribute__((ext_vector_type(4))) float f32x4;

__device__ __forceinline__ ushort f2bf(float f) {
    union { float f; unsigned int u; } v; v.f = f;
    unsigned int u = v.u;
    return (ushort)((u + 0x7FFFu + ((u >> 16) & 1u)) >> 16);
}
__device__ __forceinline__ float sigm(float x) { return 1.f / (1.f + __expf(-x)); }
__device__ __forceinline__ float ftanh(float x) {
    float e = __expf(2.f * x);
    return 1.f - 2.f / (e + 1.f);
}

// ---- prep: repack W rows 32..1055 into MFMA-fragment-major bf16 layout ----
__global__ void prep_w2(const float* __restrict__ W, ushort* __restrict__ W2) {
    int nt = blockIdx.x;          // 0..447 (16-col n-tile)
    int ki = blockIdx.y;          // 0..31
    int lane = threadIdx.x;
    int n = nt * 16 + (lane & 15);
    int k = ki * 32 + (lane >> 4) * 8;
    size_t off = ((size_t)(nt * 32 + ki) * 64 + lane) * 8;
    #pragma unroll
    for (int e = 0; e < 8; ++e)
        W2[off + e] = f2bf(W[(size_t)(32 + k + e) * G7 + n]);
}

// ---- prep: G0[type][n] = b[n] + embed[type] @ W[0:32] ----
__global__ void prep_g0(const float* __restrict__ W, const float* __restrict__ embed,
                        const float* __restrict__ bias, float* __restrict__ G0) {
    int n = blockIdx.x * 256 + threadIdx.x;
    int ty = blockIdx.y;
    float acc = bias[n];
    for (int p = 0; p < PP; ++p)
        acc += embed[ty * PP + p] * W[(size_t)p * G7 + n];
    G0[(size_t)ty * G7 + n] = acc;
}

// ---- prep: A3 (ki-major fragment layout) from h0; state init ----
__global__ void prep_init(const float* __restrict__ h0, const float* __restrict__ c0,
                          ushort* __restrict__ A3, float* __restrict__ c_state,
                          float* __restrict__ ctgt_state) {
    int i = blockIdx.x * 256 + threadIdx.x;
    int b = i >> 10, k = i & 1023;
    int lane = (b & 15) | (((k >> 3) & 3) << 4);
    size_t off = ((size_t)((k >> 5) * 8 + (b >> 4)) * 64 + lane) * 8 + (k & 7);
    A3[off] = f2bf(h0[i]);
    c_state[i] = c0[i];
    ctgt_state[i] = c0[i];
}

// ---- GEMM phase: block bt (32 cols), 8 waves = 2 n-halves x 4 k-quarters ----
__device__ __forceinline__ void gemm_phase(int bt, int wave, int lane,
    const ushort* __restrict__ W2, const ushort* __restrict__ a_read,
    float* __restrict__ Gbuf, f32x4 (*pbuf)[2][512])
{
    const int nh = wave & 1, kq = wave >> 1;
    f32x4 acc[8] = {};
    if (bt >= 0) {
        const short8* Av = reinterpret_cast<const short8*>(a_read) + kq * 4096 + lane;
        const short8* Wv = reinterpret_cast<const short8*>(W2)
                         + ((size_t)(bt * 2 + nh) * 32 + kq * 8) * 64 + lane;
        #pragma unroll
        for (int ki = 0; ki < 8; ++ki) {
            short8 wf = Wv[ki * 64];
            #pragma unroll
            for (int bf = 0; bf < 8; ++bf) {
                short8 af = Av[ki * 512 + bf * 64];
                acc[bf] = __builtin_amdgcn_mfma_f32_16x16x32_bf16(af, wf, acc[bf], 0, 0, 0);
            }
        }
        if (kq > 0) {
            #pragma unroll
            for (int bf = 0; bf < 8; ++bf)
                pbuf[kq - 1][nh][bf * 64 + lane] = acc[bf];
        }
    }
    __syncthreads();
    if (bt >= 0 && kq == 0) {
        const int rb = (lane >> 4) * 4;
        const int nn = bt * 32 + nh * 16 + (lane & 15);
        #pragma unroll
        for (int bf = 0; bf < 8; ++bf) {
            f32x4 s = acc[bf];
            s += pbuf[0][nh][bf * 64 + lane];
            s += pbuf[1][nh][bf * 64 + lane];
            s += pbuf[2][nh][bf * 64 + lane];
            const int b0r = bf * 16 + rb;
            #pragma unroll
            for (int r = 0; r < 4; ++r)
                Gbuf[(size_t)(b0r + r) * G7 + nn] = s[r];
        }
    }
}

// ---- epilogue: one (b,h) element ----
__device__ __forceinline__ void epi_elem(int t, int eb, int eh,
    const float* __restrict__ Gbuf, const float* __restrict__ G0,
    const float* __restrict__ dts, const int* __restrict__ types,
    float& c, float& ctgt, float* __restrict__ out, ushort* __restrict__ a_write)
{
    const int ty = types[t * BB + eb];
    const float dt = dts[t * BB + eb];
    const float* gP  = Gbuf + (size_t)eb * G7 + eh;
    const float* g0p = G0 + (size_t)ty * G7 + eh;
    float pre[7];
    #pragma unroll
    for (int g = 0; g < 7; ++g)
        pre[g] = gP[g * HH] + g0p[g * HH];

    float inpt   = sigm(pre[0]);
    float forget = sigm(pre[1]);
    float output = sigm(pre[2]);
    float itg    = sigm(pre[3]);
    float ftg    = sigm(pre[4]);
    float z      = ftanh(pre[5]);
    float x8     = 8.f * pre[6];
    float sp     = fmaxf(x8, 0.f) + __logf(1.f + __expf(-fabsf(x8)));
    float decay  = sp * 0.125f;

    float c_i      = forget * c + inpt * z;
    float h_i      = output * ftanh(c_i);
    float ctgt_new = ftg * ctgt + itg * z;
    float edt      = __expf(-decay * dt);
    float c_new    = ctgt_new + (c_i - ctgt_new) * edt;
    float h_new    = output * ftanh(c_new);

    const size_t OS = (size_t)TT * BB * HH;
    size_t ob = (size_t)t * BB * HH + (size_t)eb * HH + eh;
    out[ob]          = h_i;
    out[OS + ob]     = h_new;
    out[2 * OS + ob] = output;
    out[3 * OS + ob] = c_i;
    out[4 * OS + ob] = ctgt_new;
    out[5 * OS + ob] = decay;

    int lane_w = (eb & 15) | (((eh >> 3) & 3) << 4);
    size_t aoff = ((size_t)((eh >> 5) * 8 + (eb >> 4)) * 64 + lane_w) * 8 + (eh & 7);
    a_write[aoff] = f2bf(h_new);
    c = c_new;
    ctgt = ctgt_new;
}

__device__ __forceinline__ int decode_bt(int bid) {
    if (bid >= 224) return -1;
    int loc = bid >> 3;            // 0..27
    int g = loc >> 2;              // gate 0..6
    int hl = loc & 3;
    return g * 32 + (bid & 7) * 4 + hl;   // 32-col tile; XCD (bid&7) owns h-range
}

// ---- persistent cooperative kernel ----
__global__ __launch_bounds__(512) void persist_kernel(
    const ushort* __restrict__ W2, const float* __restrict__ G0,
    const float* __restrict__ dts, const int* __restrict__ types,
    ushort* __restrict__ a3_0, ushort* __restrict__ a3_1,
    float* __restrict__ Gbuf, float* __restrict__ c_state,
    float* __restrict__ ctgt_state, float* __restrict__ out)
{
    cg::grid_group grid = cg::this_grid();
    __shared__ f32x4 pbuf[3][2][512];
    const int tid = threadIdx.x, bid = blockIdx.x;
    const int lane = tid & 63, wave = tid >> 6;
    const int bt = decode_bt(bid);
    // epilogue element (XCD-matched to the blocks producing its h-slice)
    const int local = (bid >> 3) * 512 + tid;     // 0..16383 per XCD
    const int eb = local >> 7;
    const int eh = (bid & 7) * 128 + (local & 127);
    const size_t si = (size_t)eb * HH + eh;
    float c = c_state[si], ctgt = ctgt_state[si];

    for (int t = 0; t < TT; ++t) {
        const ushort* a_read = (t & 1) ? a3_1 : a3_0;
        ushort* a_write      = (t & 1) ? a3_0 : a3_1;
        gemm_phase(bt, wave, lane, W2, a_read, Gbuf, pbuf);
        grid.sync();
        epi_elem(t, eb, eh, Gbuf, G0, dts, types, c, ctgt, out, a_write);
        grid.sync();
    }
}

// ---- fallback per-step kernels (if cooperative launch unavailable) ----
__global__ __launch_bounds__(512) void gemm_step(
    const ushort* __restrict__ W2, const ushort* __restrict__ a_read,
    float* __restrict__ Gbuf)
{
    __shared__ f32x4 pbuf[3][2][512];
    const int tid = threadIdx.x;
    gemm_phase(decode_bt(blockIdx.x), tid >> 6, tid & 63, W2, a_read, Gbuf, pbuf);
}

__global__ __launch_bounds__(512) void epi_step(
    const float* __restrict__ Gbuf, const float* __restrict__ G0,
    const float* __restrict__ dts, const int* __restrict__ types,
    float* __restrict__ c_state, float* __restrict__ ctgt_state,
    float* __restrict__ out, ushort* __restrict__ a_write, int t)
{
    const int bid = blockIdx.x, tid = threadIdx.x;
    const int local = (bid >> 3) * 512 + tid;
    const int eb = local >> 7;
    const int eh = (bid & 7) * 128 + (local & 127);
    const size_t si = (size_t)eb * HH + eh;
    float c = c_state[si], ctgt = ctgt_state[si];
    epi_elem(t, eb, eh, Gbuf, G0, dts, types, c, ctgt, out, a_write);
    c_state[si] = c;
    ctgt_state[si] = ctgt;
}

extern "C" void kernel_launch(void* const* d_in, const int* in_sizes, int n_in,
                              void* d_out, int out_size, void* d_ws, size_t ws_size,
                              hipStream_t stream) {
    const float* seq_dt    = (const float*)d_in[0];
    const int*   seq_types = (const int*)d_in[1];
    const float* h0        = (const float*)d_in[2];
    const float* c0        = (const float*)d_in[3];
    const float* embed     = (const float*)d_in[4];
    const float* W         = (const float*)d_in[5];
    const float* bias      = (const float*)d_in[6];
    float* out = (float*)d_out;

    char* ws = (char*)d_ws;
    ushort* W2  = (ushort*)ws;                  // 14,680,064
    float*  G0b = (float*)(ws + 14680064);      //    946,176
    ushort* a30 = (ushort*)(ws + 15626240);     //    262,144
    ushort* a31 = (ushort*)(ws + 15888384);     //    262,144
    float*  cs  = (float*)(ws + 16150528);      //    524,288
    float*  cts = (float*)(ws + 16674816);      //    524,288
    float*  Gb  = (float*)(ws + 17199104);      //  3,670,016  (end ~20.9 MB)

    hipLaunchKernelGGL(prep_w2, dim3(448, 32), dim3(64), 0, stream, W, W2);
    hipLaunchKernelGGL(prep_g0, dim3(28, 33), dim3(256), 0, stream, W, embed, bias, G0b);
    hipLaunchKernelGGL(prep_init, dim3(512), dim3(256), 0, stream, h0, c0, a30, cs, cts);

    const ushort* W2c = W2; const float* G0c = G0b;
    void* args[] = {(void*)&W2c, (void*)&G0c, (void*)&seq_dt, (void*)&seq_types,
                    (void*)&a30, (void*)&a31, (void*)&Gb, (void*)&cs, (void*)&cts,
                    (void*)&out};
    hipError_t e = hipLaunchCooperativeKernel(persist_kernel, dim3(256), dim3(512),
                                              args, 0, stream);
    if (e != hipSuccess) {
        // fallback: per-step two-kernel pipeline
        for (int t = 0; t < TT; ++t) {
            const ushort* ar = (t & 1) ? a31 : a30;
            ushort*       aw = (t & 1) ? a30 : a31;
            hipLaunchKernelGGL(gemm_step, dim3(256), dim3(512), 0, stream, W2, ar, Gb);
            hipLaunchKernelGGL(epi_step, dim3(256), dim3(512), 0, stream,
                               Gb, G0b, seq_dt, seq_types, cs, cts, out, aw, t);
        }
    }
}

// Round 5
// 1444.503 us; speedup vs baseline: 6.5879x; 6.5879x over previous
//
#include <hip/hip_runtime.h>
#include <hip/hip_bf16.h>

#define TT 128
#define BB 128
#define HH 1024
#define PP 32
#define G7 7168

typedef __attribute__((ext_vector_type(8))) short short8;
typedef __attribute__((ext_vector_type(4))) float f32x4;

__device__ __forceinline__ ushort f2bf(float f) {
    union { float f; unsigned int u; } v; v.f = f;
    unsigned int u = v.u;
    return (ushort)((u + 0x7FFFu + ((u >> 16) & 1u)) >> 16);
}
__device__ __forceinline__ float sigm(float x) { return 1.f / (1.f + __expf(-x)); }
__device__ __forceinline__ float ftanh(float x) {
    float e = __expf(2.f * x);
    return 1.f - 2.f / (e + 1.f);
}

// ---- prep: repack W rows 32..1055 into MFMA-fragment-major bf16 layout ----
// W2[(nt*32 + ki)*64 + lane][e] = W[32 + ki*32 + (lane>>4)*8 + e][nt*16 + (lane&15)]
__global__ void prep_w2(const float* __restrict__ W, ushort* __restrict__ W2) {
    int nt = blockIdx.x;          // 0..447 (16-col n-tile)
    int ki = blockIdx.y;          // 0..31
    int lane = threadIdx.x;
    int n = nt * 16 + (lane & 15);
    int k = ki * 32 + (lane >> 4) * 8;
    size_t off = ((size_t)(nt * 32 + ki) * 64 + lane) * 8;
    #pragma unroll
    for (int e = 0; e < 8; ++e)
        W2[off + e] = f2bf(W[(size_t)(32 + k + e) * G7 + n]);
}

// ---- prep: G0[type][n] = b[n] + embed[type] @ W[0:32] ----
__global__ void prep_g0(const float* __restrict__ W, const float* __restrict__ embed,
                        const float* __restrict__ bias, float* __restrict__ G0) {
    int n = blockIdx.x * 256 + threadIdx.x;
    int ty = blockIdx.y;
    float acc = bias[n];
    for (int p = 0; p < PP; ++p)
        acc += embed[ty * PP + p] * W[(size_t)p * G7 + n];
    G0[(size_t)ty * G7 + n] = acc;
}

// ---- prep: A3 (ki-major fragment layout) from h0; state init ----
// A3[((k>>5)*8 + (b>>4))*64 + lane][e], lane = (b&15)|(((k>>3)&3)<<4), e = k&7
__global__ void prep_init(const float* __restrict__ h0, const float* __restrict__ c0,
                          ushort* __restrict__ A3, float* __restrict__ c_state,
                          float* __restrict__ ctgt_state) {
    int i = blockIdx.x * 256 + threadIdx.x;
    int b = i >> 10, k = i & 1023;
    int lane = (b & 15) | (((k >> 3) & 3) << 4);
    size_t off = ((size_t)((k >> 5) * 8 + (b >> 4)) * 64 + lane) * 8 + (k & 7);
    A3[off] = f2bf(h0[i]);
    c_state[i] = c0[i];
    ctgt_state[i] = c0[i];
}

// ---- per-step fused kernel ----
// grid 512 = 64 h-tiles x 8 b-frags; block 896 thr = 14 waves = 7 gates x 2 K-halves.
// 2 blocks/CU -> 28 waves/CU = 7 waves/SIMD for latency hiding.
__global__ __launch_bounds__(896) void step_kernel(
    const ushort* __restrict__ W2, const float* __restrict__ G0,
    const float* __restrict__ dts, const int* __restrict__ types,
    const ushort* __restrict__ a_read, ushort* __restrict__ a_write,
    float* __restrict__ c_state, float* __restrict__ ctgt_state,
    float* __restrict__ out, int t)
{
    __shared__ f32x4 pbuf[7][64];       // K-half partials
    __shared__ float gbuf[7][16][16];   // final gate pre-activations
    const int tid = threadIdx.x;
    const int wave = tid >> 6, lane = tid & 63;
    const int g = wave >> 1, kh = wave & 1;
    // XCD-pin: bid&7 = XCD (round-robin dispatch); XCD x owns h-cols [x*128,(x+1)*128)
    const int bid = blockIdx.x;
    const int ht = (bid & 7) * 8 + ((bid >> 3) & 7);  // 0..63
    const int bf = bid >> 6;                          // 0..7 (16-row b-frag)
    const int nt = g * 64 + ht;

    const short8* Av = reinterpret_cast<const short8*>(a_read) + bf * 64 + lane;
    const short8* Wv = reinterpret_cast<const short8*>(W2)
                     + (size_t)nt * 2048 + kh * 16 * 64 + lane;

    f32x4 acc = {};
    #pragma unroll 8
    for (int ki = 0; ki < 16; ++ki) {
        short8 af = Av[(kh * 16 + ki) * 512];
        short8 wf = Wv[ki * 64];
        acc = __builtin_amdgcn_mfma_f32_16x16x32_bf16(af, wf, acc, 0, 0, 0);
    }

    if (kh == 1) pbuf[g][lane] = acc;
    __syncthreads();
    if (kh == 0) {
        f32x4 o = pbuf[g][lane];
        acc += o;
        // C/D layout (verified R2): b-row = (lane>>4)*4 + r, h-col = lane&15
        const int rb = (lane >> 4) * 4;
        const int lr = lane & 15;
        #pragma unroll
        for (int r = 0; r < 4; ++r)
            gbuf[g][rb + r][lr] = acc[r];
    }
    __syncthreads();

    // epilogue: 256 elements (16 b-rows x 16 h-cols)
    if (tid < 256) {
        const int br = tid >> 4, hc = tid & 15;
        const int b = bf * 16 + br;
        const int h = ht * 16 + hc;
        const int ty = types[t * BB + b];
        const float dt = dts[t * BB + b];
        const float* g0p = G0 + (size_t)ty * G7 + h;
        float pre[7];
        #pragma unroll
        for (int gg = 0; gg < 7; ++gg)
            pre[gg] = gbuf[gg][br][hc] + g0p[gg * HH];

        float inpt   = sigm(pre[0]);
        float forget = sigm(pre[1]);
        float output = sigm(pre[2]);
        float itg    = sigm(pre[3]);
        float ftg    = sigm(pre[4]);
        float z      = ftanh(pre[5]);
        float x8     = 8.f * pre[6];
        float sp     = fmaxf(x8, 0.f) + __logf(1.f + __expf(-fabsf(x8)));
        float decay  = sp * 0.125f;

        const size_t si = (size_t)b * HH + h;
        float c    = c_state[si];
        float ctgt = ctgt_state[si];
        float c_i      = forget * c + inpt * z;
        float h_i      = output * ftanh(c_i);
        float ctgt_new = ftg * ctgt + itg * z;
        float edt      = __expf(-decay * dt);
        float c_new    = ctgt_new + (c_i - ctgt_new) * edt;
        float h_new    = output * ftanh(c_new);

        const size_t OS = (size_t)TT * BB * HH;
        size_t ob = (size_t)t * BB * HH + si;
        out[ob]          = h_i;
        out[OS + ob]     = h_new;
        out[2 * OS + ob] = output;
        out[3 * OS + ob] = c_i;
        out[4 * OS + ob] = ctgt_new;
        out[5 * OS + ob] = decay;
        c_state[si]    = c_new;
        ctgt_state[si] = ctgt_new;
        // h_new -> next step's A3 (ki-major fragment layout)
        int lane_w = (b & 15) | (((h >> 3) & 3) << 4);
        size_t aoff = ((size_t)((h >> 5) * 8 + (b >> 4)) * 64 + lane_w) * 8 + (h & 7);
        a_write[aoff] = f2bf(h_new);
    }
}

extern "C" void kernel_launch(void* const* d_in, const int* in_sizes, int n_in,
                              void* d_out, int out_size, void* d_ws, size_t ws_size,
                              hipStream_t stream) {
    const float* seq_dt    = (const float*)d_in[0];
    const int*   seq_types = (const int*)d_in[1];
    const float* h0        = (const float*)d_in[2];
    const float* c0        = (const float*)d_in[3];
    const float* embed     = (const float*)d_in[4];
    const float* W         = (const float*)d_in[5];
    const float* bias      = (const float*)d_in[6];
    float* out = (float*)d_out;

    char* ws = (char*)d_ws;
    ushort* W2  = (ushort*)ws;                  // 14,680,064
    float*  G0b = (float*)(ws + 14680064);      //    946,176
    ushort* a30 = (ushort*)(ws + 15626240);     //    262,144
    ushort* a31 = (ushort*)(ws + 15888384);     //    262,144
    float*  cs  = (float*)(ws + 16150528);      //    524,288
    float*  cts = (float*)(ws + 16674816);      //    524,288

    hipLaunchKernelGGL(prep_w2, dim3(448, 32), dim3(64), 0, stream, W, W2);
    hipLaunchKernelGGL(prep_g0, dim3(28, 33), dim3(256), 0, stream, W, embed, bias, G0b);
    hipLaunchKernelGGL(prep_init, dim3(512), dim3(256), 0, stream, h0, c0, a30, cs, cts);

    for (int t = 0; t < TT; ++t) {
        const ushort* ar = (t & 1) ? a31 : a30;
        ushort*       aw = (t & 1) ? a30 : a31;
        hipLaunchKernelGGL(step_kernel, dim3(512), dim3(896), 0, stream,
                           W2, G0b, seq_dt, seq_types, ar, aw, cs, cts, out, t);
    }
}

// Round 6
// 1070.184 us; speedup vs baseline: 8.8921x; 1.3498x over previous
//
#include <hip/hip_runtime.h>
#include <hip/hip_bf16.h>

#define TT 128
#define BB 128
#define HH 1024
#define PP 32
#define G7 7168

typedef __attribute__((ext_vector_type(8))) short short8;
typedef __attribute__((ext_vector_type(4))) float f32x4;

__device__ __forceinline__ ushort f2bf(float f) {
    union { float f; unsigned int u; } v; v.f = f;
    unsigned int u = v.u;
    return (ushort)((u + 0x7FFFu + ((u >> 16) & 1u)) >> 16);
}
__device__ __forceinline__ float sigm(float x) { return 1.f / (1.f + __expf(-x)); }
__device__ __forceinline__ float ftanh(float x) {
    float e = __expf(2.f * x);
    return 1.f - 2.f / (e + 1.f);
}

// ---- prep: repack W rows 32..1055 into MFMA-fragment-major bf16 layout ----
// W2[(nt*32 + ki)*64 + lane][e] = W[32 + ki*32 + (lane>>4)*8 + e][nt*16 + (lane&15)]
__global__ void prep_w2(const float* __restrict__ W, ushort* __restrict__ W2) {
    int nt = blockIdx.x;          // 0..447 (16-col n-tile)
    int ki = blockIdx.y;          // 0..31
    int lane = threadIdx.x;
    int n = nt * 16 + (lane & 15);
    int k = ki * 32 + (lane >> 4) * 8;
    size_t off = ((size_t)(nt * 32 + ki) * 64 + lane) * 8;
    #pragma unroll
    for (int e = 0; e < 8; ++e)
        W2[off + e] = f2bf(W[(size_t)(32 + k + e) * G7 + n]);
}

// ---- prep: G0[type][n] = b[n] + embed[type] @ W[0:32] ----
__global__ void prep_g0(const float* __restrict__ W, const float* __restrict__ embed,
                        const float* __restrict__ bias, float* __restrict__ G0) {
    int n = blockIdx.x * 256 + threadIdx.x;
    int ty = blockIdx.y;
    float acc = bias[n];
    for (int p = 0; p < PP; ++p)
        acc += embed[ty * PP + p] * W[(size_t)p * G7 + n];
    G0[(size_t)ty * G7 + n] = acc;
}

// ---- prep: A4 layout from h0; state init ----
// A4 index: (((bq*32 + ki)*2 + bfr)*64 + lane)*8 + e
//   bq=b>>5, ki=k>>5, bfr=(b>>4)&1, lane=(b&15)|(((k>>3)&3)<<4), e=k&7
__global__ void prep_init(const float* __restrict__ h0, const float* __restrict__ c0,
                          ushort* __restrict__ A4, float* __restrict__ c_state,
                          float* __restrict__ ctgt_state) {
    int i = blockIdx.x * 256 + threadIdx.x;
    int b = i >> 10, k = i & 1023;
    int bq = b >> 5, bfr = (b >> 4) & 1, ki = k >> 5;
    int lane = (b & 15) | (((k >> 3) & 3) << 4);
    size_t off = ((size_t)(((bq * 32 + ki) * 2 + bfr) * 64) + lane) * 8 + (k & 7);
    A4[off] = f2bf(h0[i]);
    c_state[i] = c0[i];
    ctgt_state[i] = c0[i];
}

// ---- per-step fused kernel ----
// grid 256 = 64 h-tiles x 4 b-quarters; block 896 thr = 14 waves = 7 gates x 2 b-frags.
// Full K=1024 per wave (no cross-wave reduce). A slice staged in LDS (64 KB).
__global__ __launch_bounds__(896) void step_kernel(
    const ushort* __restrict__ W2, const float* __restrict__ G0,
    const float* __restrict__ dts, const int* __restrict__ types,
    const ushort* __restrict__ a_read, ushort* __restrict__ a_write,
    float* __restrict__ c_state, float* __restrict__ ctgt_state,
    float* __restrict__ out, int t)
{
    __shared__ short8 Albuf[4096];     // 64 KB: [ki 0..31][bfr 0..1][lane 0..63] short8
    __shared__ float gbuf[7][32][16];  // 14 KB
    const int tid = threadIdx.x;
    const int wave = tid >> 6, lane = tid & 63;
    const int g = wave >> 1, bfr = wave & 1;
    const int bid = blockIdx.x;
    // XCD-pin: bid&7 = XCD; XCD x owns h-cols [x*128,(x+1)*128)
    const int ht = (bid & 7) * 8 + ((bid >> 3) & 7);  // 0..63
    const int bq = bid >> 6;                          // 0..3 (32-row b-quarter)

    // ---- stage this b-quarter's A slice (64 KB, linear copy) ----
    const short8* Asrc = reinterpret_cast<const short8*>(a_read) + bq * 4096;
    #pragma unroll
    for (int r = 0; r < 4; ++r)
        Albuf[r * 896 + tid] = Asrc[r * 896 + tid];
    if (tid < 512) Albuf[3584 + tid] = Asrc[3584 + tid];
    __syncthreads();

    // ---- K-loop: 32 MFMA over K=1024, 2 accumulator chains for ILP ----
    const short8* Wv = reinterpret_cast<const short8*>(W2)
                     + (size_t)(g * 64 + ht) * 2048 + lane;
    f32x4 acc0 = {}, acc1 = {};
    #pragma unroll 8
    for (int ki = 0; ki < 32; ki += 2) {
        short8 a0 = Albuf[(ki * 2 + bfr) * 64 + lane];
        short8 w0 = Wv[ki * 64];
        short8 a1 = Albuf[(ki * 2 + 2 + bfr) * 64 + lane];
        short8 w1 = Wv[(ki + 1) * 64];
        acc0 = __builtin_amdgcn_mfma_f32_16x16x32_bf16(a0, w0, acc0, 0, 0, 0);
        acc1 = __builtin_amdgcn_mfma_f32_16x16x32_bf16(a1, w1, acc1, 0, 0, 0);
    }
    acc0 = acc0 + acc1;

    // C/D layout (verified): b-row = (lane>>4)*4 + r, h-col = lane&15
    const int rb = (lane >> 4) * 4, lr = lane & 15;
    #pragma unroll
    for (int r = 0; r < 4; ++r)
        gbuf[g][bfr * 16 + rb + r][lr] = acc0[r];
    __syncthreads();

    // ---- epilogue: 512 elements (32 b-rows x 16 h-cols) ----
    if (tid < 512) {
        const int br = tid >> 4, hc = tid & 15;
        const int b = bq * 32 + br;
        const int h = ht * 16 + hc;
        const int ty = types[t * BB + b];
        const float dt = dts[t * BB + b];
        const float* g0p = G0 + (size_t)ty * G7 + h;
        float pre[7];
        #pragma unroll
        for (int gg = 0; gg < 7; ++gg)
            pre[gg] = gbuf[gg][br][hc] + g0p[gg * HH];

        float inpt   = sigm(pre[0]);
        float forget = sigm(pre[1]);
        float output = sigm(pre[2]);
        float itg    = sigm(pre[3]);
        float ftg    = sigm(pre[4]);
        float z      = ftanh(pre[5]);
        float x8     = 8.f * pre[6];
        float sp     = fmaxf(x8, 0.f) + __logf(1.f + __expf(-fabsf(x8)));
        float decay  = sp * 0.125f;

        const size_t si = (size_t)b * HH + h;
        float c    = c_state[si];
        float ctgt = ctgt_state[si];
        float c_i      = forget * c + inpt * z;
        float h_i      = output * ftanh(c_i);
        float ctgt_new = ftg * ctgt + itg * z;
        float edt      = __expf(-decay * dt);
        float c_new    = ctgt_new + (c_i - ctgt_new) * edt;
        float h_new    = output * ftanh(c_new);

        const size_t OS = (size_t)TT * BB * HH;
        size_t ob = (size_t)t * BB * HH + si;
        out[ob]          = h_i;
        out[OS + ob]     = h_new;
        out[2 * OS + ob] = output;
        out[3 * OS + ob] = c_i;
        out[4 * OS + ob] = ctgt_new;
        out[5 * OS + ob] = decay;
        c_state[si]    = c_new;
        ctgt_state[si] = ctgt_new;
        // h_new -> next step's A4 layout
        int ki_w = h >> 5;
        int lane_w = (b & 15) | (((h >> 3) & 3) << 4);
        size_t aoff = ((size_t)((((b >> 5) * 32 + ki_w) * 2 + ((b >> 4) & 1)) * 64) + lane_w) * 8 + (h & 7);
        a_write[aoff] = f2bf(h_new);
    }
}

extern "C" void kernel_launch(void* const* d_in, const int* in_sizes, int n_in,
                              void* d_out, int out_size, void* d_ws, size_t ws_size,
                              hipStream_t stream) {
    const float* seq_dt    = (const float*)d_in[0];
    const int*   seq_types = (const int*)d_in[1];
    const float* h0        = (const float*)d_in[2];
    const float* c0        = (const float*)d_in[3];
    const float* embed     = (const float*)d_in[4];
    const float* W         = (const float*)d_in[5];
    const float* bias      = (const float*)d_in[6];
    float* out = (float*)d_out;

    char* ws = (char*)d_ws;
    ushort* W2  = (ushort*)ws;                  // 14,680,064
    float*  G0b = (float*)(ws + 14680064);      //    946,176
    ushort* a40 = (ushort*)(ws + 15626240);     //    262,144
    ushort* a41 = (ushort*)(ws + 15888384);     //    262,144
    float*  cs  = (float*)(ws + 16150528);      //    524,288
    float*  cts = (float*)(ws + 16674816);      //    524,288

    hipLaunchKernelGGL(prep_w2, dim3(448, 32), dim3(64), 0, stream, W, W2);
    hipLaunchKernelGGL(prep_g0, dim3(28, 33), dim3(256), 0, stream, W, embed, bias, G0b);
    hipLaunchKernelGGL(prep_init, dim3(512), dim3(256), 0, stream, h0, c0, a40, cs, cts);

    for (int t = 0; t < TT; ++t) {
        const ushort* ar = (t & 1) ? a41 : a40;
        ushort*       aw = (t & 1) ? a40 : a41;
        hipLaunchKernelGGL(step_kernel, dim3(256), dim3(896), 0, stream,
                           W2, G0b, seq_dt, seq_types, ar, aw, cs, cts, out, t);
    }
}